// Round 3
// baseline (312.364 us; speedup 1.0000x reference)
//
#include <hip/hip_runtime.h>
#include <hip/hip_bf16.h>
#include <cstdint>
#include <cstddef>

typedef __bf16 bf16;
typedef __attribute__((ext_vector_type(8))) __bf16 bf16x8;
typedef __attribute__((ext_vector_type(4))) float f32x4;

static_assert(sizeof(bf16x8) == 16, "bf16x8 must be 16B");

#define NTASK 34

__device__ __forceinline__ f32x4 mfma16(bf16x8 a, bf16x8 b, f32x4 c) {
  return __builtin_amdgcn_mfma_f32_16x16x32_bf16(a, b, c, 0, 0, 0);
}

__device__ __forceinline__ void gload_lds16(const void* g, void* l) {
  __builtin_amdgcn_global_load_lds((__attribute__((address_space(1))) void*)g,
                                   (__attribute__((address_space(3))) void*)l,
                                   16, 0, 0);
}

#define LDS_BARRIER do { \
  asm volatile("s_waitcnt lgkmcnt(0)" ::: "memory"); \
  __builtin_amdgcn_s_barrier(); \
} while (0)

// ---------------- prep kernels ----------------

// Weights -> bf16 MFMA-B-fragment chunks, per-task consumption-ordered stream:
// chunk (n*16 + phase0 + ks), within-chunk (ct*64+l)*8+j holds
// W[n][k=ks*32+(l>>4)*8+j][col=ct*16+(l&15)]
__global__ void prep_w(const float* __restrict__ src, bf16* __restrict__ dst,
                       int ksteps, int phase0, int total) {
  int idx = blockIdx.x * 256 + threadIdx.x;
  if (idx >= total) return;
  int per_n = ksteps * 512;
  int n = idx / per_n;
  int r = idx - n * per_n;
  int ks = r >> 9;
  int ct = (r >> 6) & 7;
  int l = r & 63;
  int k0 = ks * 32 + ((l >> 4) << 3);
  int col = ct * 16 + (l & 15);
  const float* s = src + ((size_t)n * (ksteps * 32) + k0) * 128 + col;
  bf16x8 v;
#pragma unroll
  for (int j = 0; j < 8; ++j) v[j] = (bf16)s[(size_t)j * 128];
  size_t chunk = (size_t)n * 16 + phase0 + ks;
  *(bf16x8*)(dst + chunk * 4096 + (ct * 64 + l) * 8) = v;
}

// state -> bf16 A-fragment order per 16-row strip
__global__ void prep_state_frags(const float* __restrict__ state, bf16* __restrict__ dst) {
  int idx = blockIdx.x * 256 + threadIdx.x;   // 524288 total
  int strip = idx >> 9;
  int r = idx & 511;
  int ks = r >> 6;
  int l = r & 63;
  int b = strip * 16 + (l & 15);
  int k0 = ks * 32 + ((l >> 4) << 3);
  const float* s = state + (size_t)b * 256 + k0;
  bf16x8 v;
#pragma unroll
  for (int j = 0; j < 8; ++j) v[j] = (bf16)s[j];
  *(bf16x8*)(dst + (size_t)idx * 8) = v;
}

__global__ void prep_langn(const float* __restrict__ lang, float* __restrict__ out) {
  __shared__ float red[2];
  int n = blockIdx.x;
  int t = threadIdx.x;
  float v = lang[(size_t)n * 128 + t];
  float ss = v * v;
#pragma unroll
  for (int m = 1; m < 64; m <<= 1) ss += __shfl_xor(ss, m);
  if ((t & 63) == 0) red[t >> 6] = ss;
  __syncthreads();
  float s = red[0] + red[1];
  float sc = 1.0f / fmaxf(sqrtf(s), 1e-8f);
  out[(size_t)n * 128 + t] = v * sc;
}

__global__ void prep_pprior(const float* __restrict__ prior, bf16* __restrict__ pp) {
  int row = blockIdx.x * 4 + (threadIdx.x >> 6);
  int lane = threadIdx.x & 63;
  float v = (lane < NTASK) ? prior[(size_t)row * NTASK + lane] : -INFINITY;
  float m = v;
#pragma unroll
  for (int mm = 1; mm < 64; mm <<= 1) m = fmaxf(m, __shfl_xor(m, mm));
  float e = (lane < NTASK) ? expf(v - m) : 0.0f;
  float s = e;
#pragma unroll
  for (int mm = 1; mm < 64; mm <<= 1) s += __shfl_xor(s, mm);
  if (lane < NTASK) pp[(size_t)row * NTASK + lane] = (bf16)(e / s);
}

// ---------------- pass 1: task-per-block fused MLP ----------------

__global__ void __launch_bounds__(512, 2)
pass1_kernel(const int* __restrict__ task_id,
             const float* __restrict__ b1, const float* __restrict__ b2,
             const float* __restrict__ b3,
             const bf16* __restrict__ wstream, const bf16* __restrict__ sf,
             const float* __restrict__ langn, const bf16* __restrict__ pp,
             float* __restrict__ cs_ws, float* __restrict__ lat_ws,
             float* __restrict__ out_tgt) {
  __shared__ __align__(16) bf16 shW[16 * 4096];     // this task's full weights, 128KB
  __shared__ __align__(16) bf16 sh_h[64][136];      // h handoff, 272B rows
  __shared__ float sh_red[64][2];                   // [row][0]=ssq, [1]=dot

  const int tid = threadIdx.x;
  const int l = tid & 63;
  const int w = tid >> 6;
  const int sp = w >> 2;          // row half (2 strips of 16)
  const int cp = w & 3;           // col quarter (32 cols)
  const int g4 = l >> 4;
  const int r16 = l & 15;
  const int n = blockIdx.x >> 6;          // task
  const int gg = blockIdx.x & 63;         // row group
  const int rows0 = gg * 256;
  const int colw = cp * 32 + r16;

  // ---- prologue: stage all 16 weight chunks, load tile-0 A-frags, biases
  const bf16* wbase = wstream + (size_t)n * 65536;
#pragma unroll
  for (int c = 0; c < 16; ++c)
    gload_lds16(wbase + c * 4096 + tid * 8, shW + c * 4096 + tid * 8);

  float b1v[2], b2v[2], b3v[2];
#pragma unroll
  for (int t = 0; t < 2; ++t) {
    b1v[t] = b1[n * 128 + colw + t * 16];
    b2v[t] = b2[n * 128 + colw + t * 16];
    b3v[t] = b3[n * 128 + colw + t * 16];
  }

  bf16x8 sfrag[2][8];
  {
    const int stb = rows0 >> 4;
#pragma unroll
    for (int s = 0; s < 2; ++s)
#pragma unroll
      for (int ks = 0; ks < 8; ++ks)
        sfrag[s][ks] = *(const bf16x8*)(sf + (size_t)(stb + sp * 2 + s) * 4096 + ks * 512 + l * 8);
  }
  __syncthreads();   // weights + frags ready (single full drain)

  const f32x4 fz = {0.f, 0.f, 0.f, 0.f};

#pragma unroll
  for (int t = 0; t < 4; ++t) {
    const int rbase = rows0 + t * 64;
    f32x4 acc[2][2] = {{fz, fz}, {fz, fz}};

    // ---- GEMM1: state x W1 (chunks 0..7), sfrag prefetched in-place for t+1
#pragma unroll
    for (int ks = 0; ks < 8; ++ks) {
      bf16x8 bf0 = *(const bf16x8*)(shW + ks * 4096 + (cp * 2 + 0) * 512 + l * 8);
      bf16x8 bf1 = *(const bf16x8*)(shW + ks * 4096 + (cp * 2 + 1) * 512 + l * 8);
      acc[0][0] = mfma16(sfrag[0][ks], bf0, acc[0][0]);
      acc[0][1] = mfma16(sfrag[0][ks], bf1, acc[0][1]);
      acc[1][0] = mfma16(sfrag[1][ks], bf0, acc[1][0]);
      acc[1][1] = mfma16(sfrag[1][ks], bf1, acc[1][1]);
      if (t < 3) {
        const int stb = (rows0 + (t + 1) * 64) >> 4;
        sfrag[0][ks] = *(const bf16x8*)(sf + (size_t)(stb + sp * 2 + 0) * 4096 + ks * 512 + l * 8);
        sfrag[1][ks] = *(const bf16x8*)(sf + (size_t)(stb + sp * 2 + 1) * 4096 + ks * 512 + l * 8);
      }
    }
    // h1 = relu(acc + b1)
#pragma unroll
    for (int s = 0; s < 2; ++s)
#pragma unroll
      for (int tt = 0; tt < 2; ++tt)
#pragma unroll
        for (int j = 0; j < 4; ++j) {
          float v = fmaxf(acc[s][tt][j] + b1v[tt], 0.0f);
          sh_h[sp * 32 + s * 16 + g4 * 4 + j][colw + tt * 16] = (bf16)v;
        }
    LDS_BARRIER;   // BAR1

    // epilogue-support loads (issued early, consumed post-GEMM3)
    int tidv[2][4]; float pwv[2][4]; float lgnv[2][2][4];
#pragma unroll
    for (int s = 0; s < 2; ++s)
#pragma unroll
      for (int j = 0; j < 4; ++j) {
        int gr = rbase + sp * 32 + s * 16 + g4 * 4 + j;
        tidv[s][j] = task_id[gr];
        pwv[s][j] = (float)pp[(size_t)gr * NTASK + n];
      }
#pragma unroll
    for (int s = 0; s < 2; ++s)
#pragma unroll
      for (int tt = 0; tt < 2; ++tt)
#pragma unroll
        for (int j = 0; j < 4; ++j)
          lgnv[s][tt][j] = langn[(size_t)tidv[s][j] * 128 + colw + tt * 16];

    // ---- GEMM2: h1 x W2 (chunks 8..11)
#pragma unroll
    for (int s = 0; s < 2; ++s)
#pragma unroll
      for (int tt = 0; tt < 2; ++tt) acc[s][tt] = fz;
#pragma unroll
    for (int ks = 0; ks < 4; ++ks) {
      bf16x8 a0 = *(const bf16x8*)&sh_h[sp * 32 + r16][ks * 32 + g4 * 8];
      bf16x8 a1 = *(const bf16x8*)&sh_h[sp * 32 + 16 + r16][ks * 32 + g4 * 8];
      bf16x8 bf0 = *(const bf16x8*)(shW + (8 + ks) * 4096 + (cp * 2 + 0) * 512 + l * 8);
      bf16x8 bf1 = *(const bf16x8*)(shW + (8 + ks) * 4096 + (cp * 2 + 1) * 512 + l * 8);
      acc[0][0] = mfma16(a0, bf0, acc[0][0]);
      acc[0][1] = mfma16(a0, bf1, acc[0][1]);
      acc[1][0] = mfma16(a1, bf0, acc[1][0]);
      acc[1][1] = mfma16(a1, bf1, acc[1][1]);
    }
    LDS_BARRIER;   // BAR2 (h1 reads done)

    // h2 = relu(acc + b2)
#pragma unroll
    for (int s = 0; s < 2; ++s)
#pragma unroll
      for (int tt = 0; tt < 2; ++tt)
#pragma unroll
        for (int j = 0; j < 4; ++j) {
          float v = fmaxf(acc[s][tt][j] + b2v[tt], 0.0f);
          sh_h[sp * 32 + s * 16 + g4 * 4 + j][colw + tt * 16] = (bf16)v;
        }
    if (tid < 128) ((float*)sh_red)[tid] = 0.0f;
    LDS_BARRIER;   // BAR3

    // ---- GEMM3: h2 x W3 (chunks 12..15)
#pragma unroll
    for (int s = 0; s < 2; ++s)
#pragma unroll
      for (int tt = 0; tt < 2; ++tt) acc[s][tt] = fz;
#pragma unroll
    for (int ks = 0; ks < 4; ++ks) {
      bf16x8 a0 = *(const bf16x8*)&sh_h[sp * 32 + r16][ks * 32 + g4 * 8];
      bf16x8 a1 = *(const bf16x8*)&sh_h[sp * 32 + 16 + r16][ks * 32 + g4 * 8];
      bf16x8 bf0 = *(const bf16x8*)(shW + (12 + ks) * 4096 + (cp * 2 + 0) * 512 + l * 8);
      bf16x8 bf1 = *(const bf16x8*)(shW + (12 + ks) * 4096 + (cp * 2 + 1) * 512 + l * 8);
      acc[0][0] = mfma16(a0, bf0, acc[0][0]);
      acc[0][1] = mfma16(a0, bf1, acc[0][1]);
      acc[1][0] = mfma16(a1, bf0, acc[1][0]);
      acc[1][1] = mfma16(a1, bf1, acc[1][1]);
    }

    // ---- epilogue A: q = acc + b3; reduce ssq & dot over the wave's 32 cols
    float qv[2][2][4];
#pragma unroll
    for (int s = 0; s < 2; ++s)
#pragma unroll
      for (int tt = 0; tt < 2; ++tt)
#pragma unroll
        for (int j = 0; j < 4; ++j) qv[s][tt][j] = acc[s][tt][j] + b3v[tt];
#pragma unroll
    for (int s = 0; s < 2; ++s)
#pragma unroll
      for (int j = 0; j < 4; ++j) {
        float ssq = qv[s][0][j] * qv[s][0][j] + qv[s][1][j] * qv[s][1][j];
        float dot = qv[s][0][j] * lgnv[s][0][j] + qv[s][1][j] * lgnv[s][1][j];
        ssq += __shfl_xor(ssq, 1); dot += __shfl_xor(dot, 1);
        ssq += __shfl_xor(ssq, 2); dot += __shfl_xor(dot, 2);
        ssq += __shfl_xor(ssq, 4); dot += __shfl_xor(dot, 4);
        ssq += __shfl_xor(ssq, 8); dot += __shfl_xor(dot, 8);
        if (r16 == 0) {
          int row = sp * 32 + s * 16 + g4 * 4 + j;
          atomicAdd(&sh_red[row][0], ssq);
          atomicAdd(&sh_red[row][1], dot);
        }
      }
    LDS_BARRIER;   // BAR4

    // ---- epilogue B: normalize, tgt, latent atomics, cos store
#pragma unroll
    for (int s = 0; s < 2; ++s)
#pragma unroll
      for (int j = 0; j < 4; ++j) {
        int row = sp * 32 + s * 16 + g4 * 4 + j;
        float2 rd = *(const float2*)&sh_red[row][0];
        float inv = rsqrtf(rd.x);
        float q0 = qv[s][0][j] * inv;
        float q1 = qv[s][1][j] * inv;
        size_t gr = (size_t)(rbase + row);
        if (tidv[s][j] == n) {
          out_tgt[gr * 128 + colw] = q0;
          out_tgt[gr * 128 + colw + 16] = q1;
        }
        float pwf = pwv[s][j];
        atomicAdd(&lat_ws[gr * 128 + colw], pwf * q0);
        atomicAdd(&lat_ws[gr * 128 + colw + 16], pwf * q1);
      }
    if (tid < 64) {
      float2 rr = *(const float2*)&sh_red[tid][0];
      cs_ws[(size_t)(rbase + tid) * NTASK + n] = rr.y * rsqrtf(rr.x);
    }
  }
}

// ---------------- pass 3: per-row combine ----------------

__global__ void __launch_bounds__(256)
pass3_kernel(const float* __restrict__ state, const float* __restrict__ cs_ws,
             const float* __restrict__ lat_ws,
             float* __restrict__ out_rep, float* __restrict__ out_ltp,
             float* __restrict__ out_lat) {
  int w = threadIdx.x >> 6, l = threadIdx.x & 63;
  size_t row = (size_t)blockIdx.x * 4 + w;
  float c = (l < NTASK) ? cs_ws[row * NTASK + l] * 10.0f : -1e30f;
  float m = c;
#pragma unroll
  for (int mm = 1; mm < 64; mm <<= 1) m = fmaxf(m, __shfl_xor(m, mm));
  float e = (l < NTASK) ? expf(c - m) : 0.0f;
  float s = e;
#pragma unroll
  for (int mm = 1; mm < 64; mm <<= 1) s += __shfl_xor(s, mm);
  float lse = logf(s);
  if (l < NTASK) out_ltp[row * NTASK + l] = c - m - lse;
  float2 lv = *(const float2*)(lat_ws + row * 128 + l * 2);
  *(float2*)(out_lat + row * 128 + l * 2) = lv;
  *(float2*)(out_rep + row * 384 + 256 + l * 2) = lv;
  float4 sv = *(const float4*)(state + row * 256 + l * 4);
  *(float4*)(out_rep + row * 384 + l * 4) = sv;
}

// ---------------- launch ----------------

extern "C" void kernel_launch(void* const* d_in, const int* in_sizes, int n_in,
                              void* d_out, int out_size, void* d_ws, size_t ws_size,
                              hipStream_t stream) {
  (void)in_sizes; (void)n_in; (void)out_size; (void)ws_size;
  const float* state = (const float*)d_in[0];
  const int* task_id = (const int*)d_in[1];
  const float* prior = (const float*)d_in[2];
  const float* W1 = (const float*)d_in[3];
  const float* b1 = (const float*)d_in[4];
  const float* W2 = (const float*)d_in[5];
  const float* b2 = (const float*)d_in[6];
  const float* W3 = (const float*)d_in[7];
  const float* b3 = (const float*)d_in[8];
  const float* lang = (const float*)d_in[9];

  char* ws = (char*)d_ws;
  bf16* wstream = (bf16*)(ws + 0);          //  4,456,448 B (34 x 16 x 4096 bf16)
  bf16* sf      = (bf16*)(ws + 4456448);    //  8,388,608 B
  float* langn  = (float*)(ws + 12845056);  //     17,408 B
  bf16* pp      = (bf16*)(ws + 12862464);   //  1,114,112 B
  float* cs_ws  = (float*)(ws + 13976576);  //  2,228,224 B
  float* lat_ws = (float*)(ws + 16204800);  //  8,388,608 B  (ends 24,593,408)

  float* out = (float*)d_out;
  float* out_rep = out;                 // [B,384]
  float* out_ltp = out + 6291456;       // [B,34]
  float* out_tgt = out + 6848512;       // [B,128]
  float* out_lat = out + 8945664;       // [B,128]

  hipMemsetAsync(lat_ws, 0, 8388608, stream);
  prep_w<<<544, 256, 0, stream>>>(W1, wstream, 8, 0, NTASK * 8 * 512);
  prep_w<<<272, 256, 0, stream>>>(W2, wstream, 4, 8, NTASK * 4 * 512);
  prep_w<<<272, 256, 0, stream>>>(W3, wstream, 4, 12, NTASK * 4 * 512);
  prep_state_frags<<<2048, 256, 0, stream>>>(state, sf);
  prep_langn<<<NTASK, 128, 0, stream>>>(lang, langn);
  prep_pprior<<<4096, 256, 0, stream>>>(prior, pp);
  pass1_kernel<<<2176, 512, 0, stream>>>(task_id, b1, b2, b3, wstream, sf,
                                         langn, pp, cs_ws, lat_ws, out_tgt);
  pass3_kernel<<<4096, 256, 0, stream>>>(state, cs_ws, lat_ws,
                                         out_rep, out_ltp, out_lat);
}